// Round 3
// baseline (222.788 us; speedup 1.0000x reference)
//
#include <hip/hip_runtime.h>
#include <stdint.h>

// N=16384 points, K=10 (fixed by setup_inputs).
#define NPTS   16384
#define TOPK   10
#define NBX    32                 // 32x32x32 cells over [-5,5]^3
#define NBK    (32 * 32 * 32)
#define XMIN   (-5.0f)
#define INVBW  (3.2f)             // 32 / 10.0
#define CELLW  (0.3125f)
#define SENT_STEP 0x4000u         // one ulp at masked-key granularity (= idx field)
#define LIGHT_MAX 1024u           // candidate cap for the 16-lane path
#define HEAVY_GRID 128

// ws layout (bytes):
//   0       accum[4] floats (sparsity, scale, opacity, smooth)
//   16      qcnt (uint)            heavy-queue counter
//   256     hist[NBK] uint  -> re-zeroed by prefix_scan, reused as cnt,
//                              then DEAD after scatter -> reused as queue[]
//   131328  base[NBK+1] uint
//   262464  r2m[NPTS] uint        (masked upper bound on 10-NN d2)
//   328064  sorted[NPTS] float4   (x,y,z,opacity) ordered by (bx,by,bz)
// memset zeroes [0, 131328).

__device__ __forceinline__ unsigned umin_(unsigned a, unsigned b) { return a < b ? a : b; }
__device__ __forceinline__ unsigned umax_(unsigned a, unsigned b) { return a > b ? a : b; }

// Branchless ascending insert (19 independent min/max).
__device__ __forceinline__ void chain_insert(unsigned a[TOPK], unsigned key) {
#pragma unroll
    for (int k = TOPK - 1; k > 0; --k) a[k] = umin_(umax_(a[k - 1], key), a[k]);
    a[0] = umin_(a[0], key);
}

__device__ __forceinline__ void ce_(unsigned &x, unsigned &y) {
    unsigned lo = umin_(x, y); y = umax_(x, y); x = lo;
}

// Bitonic merge network for a length-10 bitonic sequence (15 CEs).
__device__ __forceinline__ void bitonic10(unsigned a[TOPK]) {
    ce_(a[0], a[8]); ce_(a[1], a[9]);
    ce_(a[0], a[4]); ce_(a[1], a[5]); ce_(a[2], a[6]); ce_(a[3], a[7]);
    ce_(a[0], a[2]); ce_(a[1], a[3]); ce_(a[4], a[6]); ce_(a[5], a[7]);
    ce_(a[0], a[1]); ce_(a[2], a[3]); ce_(a[4], a[5]); ce_(a[6], a[7]); ce_(a[8], a[9]);
}

// Merge two sorted 10-lists: ours + partner lane's (halver + bitonic net).
__device__ __forceinline__ void merge_shfl(unsigned a[TOPK], int w) {
    unsigned b[TOPK];
#pragma unroll
    for (int k = 0; k < TOPK; ++k) b[k] = (unsigned)__shfl_xor((int)a[k], w, 64);
#pragma unroll
    for (int k = 0; k < TOPK; ++k) a[k] = umin_(a[k], b[TOPK - 1 - k]);
    bitonic10(a);
}

// Merge a sorted 10-array (same in all lanes) into our sorted top-10.
__device__ __forceinline__ void merge_arr(unsigned a[TOPK], const unsigned* b) {
#pragma unroll
    for (int k = 0; k < TOPK; ++k) a[k] = umin_(a[k], b[TOPK - 1 - k]);
    bitonic10(a);
}

__device__ __forceinline__ int cellf(float v) {
    int b = (int)((v - XMIN) * INVBW);
    return min(max(b, 0), NBX - 1);
}

// ---- fused trivial losses + 3-D cell histogram ----------------------------
__global__ __launch_bounds__(256) void setup_kernel(
    const float* __restrict__ pos, const float* __restrict__ opac,
    const float* __restrict__ scales, float* __restrict__ accum,
    unsigned* __restrict__ hist)
{
    int i = blockIdx.x * 256 + threadIdx.x;
    float o = opac[i];
    float d = o - 0.5f;
    float s_sp = fabsf(o);
    float s_op = d * d;
    float s_sc = fabsf(scales[3 * i] - 1.0f) + fabsf(scales[3 * i + 1] - 1.0f)
               + fabsf(scales[3 * i + 2] - 1.0f);
    int bx = cellf(pos[3 * i]);
    int by = cellf(pos[3 * i + 1]);
    int bz = cellf(pos[3 * i + 2]);
    atomicAdd(&hist[(bx << 10) | (by << 5) | bz], 1u);
#pragma unroll
    for (int off = 32; off > 0; off >>= 1) {
        s_sp += __shfl_down(s_sp, off, 64);
        s_sc += __shfl_down(s_sc, off, 64);
        s_op += __shfl_down(s_op, off, 64);
    }
    if ((threadIdx.x & 63) == 0) {
        atomicAdd(&accum[0], s_sp);
        atomicAdd(&accum[1], s_sc);
        atomicAdd(&accum[2], s_op);
    }
}

// Exclusive scan over 32768 bins: shfl-based (2 barriers total).
// Also re-zeroes hist in place (it becomes the scatter cnt array).
__global__ __launch_bounds__(1024) void prefix_scan(
    unsigned* __restrict__ hist, unsigned* __restrict__ base)
{
    __shared__ unsigned wsum[16];
    const int t = threadIdx.x;
    const int lane = t & 63, wid = t >> 6;
    unsigned loc[32];
    uint4* h4 = (uint4*)(hist + t * 32);
#pragma unroll
    for (int j = 0; j < 8; ++j) {
        uint4 h = h4[j];
        loc[4 * j + 0] = h.x; loc[4 * j + 1] = h.y;
        loc[4 * j + 2] = h.z; loc[4 * j + 3] = h.w;
    }
    unsigned run = 0;
#pragma unroll
    for (int j = 0; j < 32; ++j) { unsigned v = loc[j]; loc[j] = run; run += v; }
    // inclusive wave scan of per-thread totals
    unsigned inc = run;
#pragma unroll
    for (int off = 1; off < 64; off <<= 1) {
        unsigned v = (unsigned)__shfl_up((int)inc, off, 64);
        if (lane >= off) inc += v;
    }
    if (lane == 63) wsum[wid] = inc;
    __syncthreads();
    if (wid == 0) {
        unsigned w = (lane < 16) ? wsum[lane] : 0u;
#pragma unroll
        for (int off = 1; off < 16; off <<= 1) {
            unsigned v = (unsigned)__shfl_up((int)w, off, 64);
            if (lane >= off) w += v;
        }
        if (lane < 16) wsum[lane] = w;       // inclusive wave sums
    }
    __syncthreads();
    const unsigned wbase = (wid > 0) ? wsum[wid - 1] : 0u;
    const unsigned tbase = wbase + inc - run;  // exclusive base for this thread
    uint4* b4 = (uint4*)(base + t * 32);
#pragma unroll
    for (int j = 0; j < 8; ++j) {
        b4[j] = make_uint4(loc[4 * j] + tbase, loc[4 * j + 1] + tbase,
                           loc[4 * j + 2] + tbase, loc[4 * j + 3] + tbase);
        h4[j] = make_uint4(0u, 0u, 0u, 0u);
    }
    if (t == 1023) base[NBK] = NPTS;
}

__global__ __launch_bounds__(256) void scatter_sorted(
    const float* __restrict__ pos, const float* __restrict__ opac,
    const unsigned* __restrict__ base, unsigned* __restrict__ cnt,
    float4* __restrict__ sorted)
{
    int i = blockIdx.x * 256 + threadIdx.x;
    float x = pos[3 * i], y = pos[3 * i + 1], z = pos[3 * i + 2];
    int b = (cellf(x) << 10) | (cellf(y) << 5) | cellf(z);
    unsigned p = base[b] + atomicAdd(&cnt[b], 1u);
    sorted[p] = make_float4(x, y, z, opac[i]);
}

// ---- pass 1: per-point upper bound on 10-NN d2 ----------------------------
__global__ __launch_bounds__(256) void knn_pass1(
    const float4* __restrict__ sorted, unsigned* __restrict__ r2m)
{
    const int t8  = blockIdx.x * 256 + threadIdx.x;
    const int s   = t8 >> 3;
    const int sub = t8 & 7;
    const int dir = sub >> 2;                  // 0 right, 1 left
    const int start = 1 + (sub & 3) * 32;
    const float4 me = sorted[s];

    unsigned a[TOPK];
#pragma unroll
    for (int k = 0; k < TOPK; ++k) a[k] = 0xFFFFFFFFu;

#pragma unroll 4
    for (int t = 0; t < 32; ++t) {
        int p = dir ? (s - start - t) : (s + start + t);
        int pc = min(max(p, 0), NPTS - 1);
        float4 c = sorted[pc];
        float dx = c.x - me.x, dy = c.y - me.y, dz = c.z - me.z;
        float d2 = fmaf(dx, dx, fmaf(dy, dy, dz * dz));
        unsigned key = (__float_as_uint(d2) & 0xFFFFC000u) | (unsigned)pc;
        if (p < 0 || p >= NPTS) key = 0xFFFFFFFFu;
        chain_insert(a, key);
    }
    merge_shfl(a, 1);
    merge_shfl(a, 2);
    merge_shfl(a, 4);
    if (sub == 0) r2m[s] = a[TOPK - 1] & 0xFFFFC000u;
}

// ---- pass 2 (light): exact 10-NN for points with <= LIGHT_MAX candidates --
// 16 lanes/point. Candidate count computed first (lanes parallel over column
// pairs); oversized points go to the heavy queue. Pair bounds for the scan
// come from classification registers via shfl (no serial base[] chain).
__global__ __launch_bounds__(256) void knn_pass2(
    const float4* __restrict__ sorted, const unsigned* __restrict__ r2m,
    const unsigned* __restrict__ base, unsigned* __restrict__ qcnt,
    int* __restrict__ queue, float* __restrict__ accum)
{
    __shared__ float ssum;
    if (threadIdx.x == 0) ssum = 0.0f;
    __syncthreads();

    const int wv  = threadIdx.x >> 6;
    const int gw  = (threadIdx.x >> 4) & 3;
    const int sub = threadIdx.x & 15;
    const int W   = blockIdx.x * 4 + wv;
    const int Q   = (W * 1531) & 4095;          // balance permutation
    const int s   = Q * 4 + gw;

    const float4 me = sorted[s];
    const unsigned sentinel = r2m[s] + SENT_STEP;
    const float R = sqrtf(__uint_as_float(sentinel)) + 1e-6f;

    const int bxlo = cellf(me.x - R), bxhi = cellf(me.x + R);
    const int bylo = cellf(me.y - R), byhi = cellf(me.y + R);
    const int bzlo = cellf(me.z - R), bzhi = cellf(me.z + R);
    const int nyw   = byhi - bylo + 1;
    const int npair = (bxhi - bxlo + 1) * nyw;

    // classification: lanes strided over column pairs
    int lo0 = 0, hi0 = 0;
    unsigned csum = 0;
    for (int pi = sub; pi < npair; pi += 16) {
        int cbx = bxlo + pi / nyw, cby = bylo + pi % nyw;
        int cb = (cbx << 10) | (cby << 5);
        int l = (int)base[cb + bzlo], h = (int)base[cb + bzhi + 1];
        if (pi < 16) { lo0 = l; hi0 = h; }
        csum += (unsigned)(h - l);
    }
#pragma unroll
    for (int off = 1; off <= 8; off <<= 1)
        csum += (unsigned)__shfl_xor((int)csum, off, 64);
    const bool heavy = csum > LIGHT_MAX;
    if (heavy && sub == 0) {
        unsigned q = atomicAdd(qcnt, 1u);
        queue[q] = s;
    }

    unsigned a[TOPK];
#pragma unroll
    for (int k = 0; k < TOPK; ++k) a[k] = sentinel;

    if (!heavy) {
        const int lane0 = (threadIdx.x & 63) - sub;   // group base lane
        for (int pi = 0; pi < npair; ++pi) {
            int lo, hi;
            if (pi < 16) {
                lo = __shfl(lo0, lane0 + pi, 64);
                hi = __shfl(hi0, lane0 + pi, 64);
            } else {
                int cbx = bxlo + pi / nyw, cby = bylo + pi % nyw;
                int cb = (cbx << 10) | (cby << 5);
                lo = (int)base[cb + bzlo]; hi = (int)base[cb + bzhi + 1];
            }
            const int niter = (hi - lo + 31) >> 5;
            int p = lo + sub;
            for (int it = 0; it < niter; ++it) {
                int p1 = p + 16;
                int pc0 = min(p,  NPTS - 1);
                int pc1 = min(p1, NPTS - 1);
                float4 c0 = sorted[pc0];
                float4 c1 = sorted[pc1];
                float dx0 = c0.x - me.x, dy0 = c0.y - me.y, dz0 = c0.z - me.z;
                float dx1 = c1.x - me.x, dy1 = c1.y - me.y, dz1 = c1.z - me.z;
                float d20 = fmaf(dx0, dx0, fmaf(dy0, dy0, dz0 * dz0));
                float d21 = fmaf(dx1, dx1, fmaf(dy1, dy1, dz1 * dz1));
                unsigned k0 = (__float_as_uint(d20) & 0xFFFFC000u) | (unsigned)pc0;
                unsigned k1 = (__float_as_uint(d21) & 0xFFFFC000u) | (unsigned)pc1;
                if (p  >= hi || pc0 == s) k0 = 0xFFFFFFFFu;
                if (p1 >= hi || pc1 == s) k1 = 0xFFFFFFFFu;
                unsigned kmin = umin_(k0, k1), kmax = umax_(k0, k1);
                if (kmin < a[TOPK - 1]) {
                    chain_insert(a, kmin);
                    if (kmax < a[TOPK - 1]) chain_insert(a, kmax);
                }
                p += 32;
            }
        }
        merge_shfl(a, 1);
        merge_shfl(a, 2);
        merge_shfl(a, 4);
        merge_shfl(a, 8);
    }

    float v = 0.0f;
    if (!heavy && sub < TOPK) {
        int j = (int)(a[sub] & 0x3FFFu);
        v = fabsf(me.w - sorted[j].w);
    }
    v += __shfl_down(v, 8, 64);
    v += __shfl_down(v, 4, 64);
    v += __shfl_down(v, 2, 64);
    v += __shfl_down(v, 1, 64);
    if (sub == 0) atomicAdd(&ssum, v);
    __syncthreads();
    if (threadIdx.x == 0) atomicAdd(&accum[3], ssum);
}

// ---- heavy path: one block per queued point -------------------------------
// Wave 0 first tightens the radius via cell-box expansion (smallest m with
// >= 11 points in [b +/- m]^3 gives r10 <= sqrt(3)*(m+1)*w), then 256 lanes
// scan pairs/candidates in parallel; merge 64-lane + cross-wave via LDS.
__global__ __launch_bounds__(256) void knn_heavy(
    const float4* __restrict__ sorted, const unsigned* __restrict__ r2m,
    const unsigned* __restrict__ base, const unsigned* __restrict__ qcnt,
    const int* __restrict__ queue, float* __restrict__ accum)
{
    __shared__ unsigned s_top[3][TOPK];
    __shared__ unsigned s_sent;
    const int lane = threadIdx.x & 63;
    const int wid  = threadIdx.x >> 6;
    const int nq   = (int)*qcnt;

    for (int qi = blockIdx.x; qi < nq; qi += HEAVY_GRID) {
        const int s = queue[qi];
        const float4 me = sorted[s];
        const unsigned sent1 = r2m[s] + SENT_STEP;

        if (wid == 0) {
            const int bx = cellf(me.x), by = cellf(me.y), bz = cellf(me.z);
            unsigned sent = sent1;
            for (int m = 1; m < 32; ++m) {
                const int xlo = max(bx - m, 0), xhi = min(bx + m, NBX - 1);
                const int ylo = max(by - m, 0), yhi = min(by + m, NBX - 1);
                const int zlo = max(bz - m, 0), zhi = min(bz + m, NBX - 1);
                const int ny = yhi - ylo + 1;
                const int np = (xhi - xlo + 1) * ny;
                unsigned c = 0;
                for (int pi = lane; pi < np; pi += 64) {
                    int cbx = xlo + pi / ny, cby = ylo + pi % ny;
                    int cb = (cbx << 10) | (cby << 5);
                    c += base[cb + zhi + 1] - base[cb + zlo];
                }
#pragma unroll
                for (int off = 32; off > 0; off >>= 1)
                    c += (unsigned)__shfl_xor((int)c, off, 64);
                if (c >= 11u) {
                    float Rb = CELLW * 1.7320508f * (float)(m + 1);
                    unsigned sb = (__float_as_uint(Rb * Rb) & 0xFFFFC000u) + SENT_STEP;
                    sent = umin_(sent1, sb);
                    break;
                }
            }
            if (lane == 0) s_sent = sent;
        }
        __syncthreads();
        const unsigned sentinel = s_sent;
        const float R = sqrtf(__uint_as_float(sentinel)) + 1e-6f;

        const int bxlo = cellf(me.x - R), bxhi = cellf(me.x + R);
        const int bylo = cellf(me.y - R), byhi = cellf(me.y + R);
        const int bzlo = cellf(me.z - R), bzhi = cellf(me.z + R);
        const int nyw   = byhi - bylo + 1;
        const int npair = (bxhi - bxlo + 1) * nyw;

        unsigned a[TOPK];
#pragma unroll
        for (int k = 0; k < TOPK; ++k) a[k] = sentinel;

        for (int pi = threadIdx.x; pi < npair; pi += 256) {
            int cbx = bxlo + pi / nyw, cby = bylo + pi % nyw;
            int cb = (cbx << 10) | (cby << 5);
            int lo = (int)base[cb + bzlo], hi = (int)base[cb + bzhi + 1];
            for (int p = lo; p < hi; ++p) {
                float4 c = sorted[p];
                float dx = c.x - me.x, dy = c.y - me.y, dz = c.z - me.z;
                float d2 = fmaf(dx, dx, fmaf(dy, dy, dz * dz));
                unsigned key = (__float_as_uint(d2) & 0xFFFFC000u) | (unsigned)p;
                if (p == s) key = 0xFFFFFFFFu;
                if (key < a[TOPK - 1]) chain_insert(a, key);
            }
        }

        merge_shfl(a, 1);  merge_shfl(a, 2);  merge_shfl(a, 4);
        merge_shfl(a, 8);  merge_shfl(a, 16); merge_shfl(a, 32);

        if (wid > 0 && lane == 0) {
#pragma unroll
            for (int k = 0; k < TOPK; ++k) s_top[wid - 1][k] = a[k];
        }
        __syncthreads();
        if (wid == 0) {
            unsigned b[TOPK];
#pragma unroll
            for (int wv = 0; wv < 3; ++wv) {
#pragma unroll
                for (int k = 0; k < TOPK; ++k) b[k] = s_top[wv][k];
                merge_arr(a, b);
            }
            float v = 0.0f;
            if (lane < TOPK) {
                int j = (int)(a[lane] & 0x3FFFu);
                v = fabsf(me.w - sorted[j].w);
            }
            v += __shfl_down(v, 8, 64);
            v += __shfl_down(v, 4, 64);
            v += __shfl_down(v, 2, 64);
            v += __shfl_down(v, 1, 64);
            if (lane == 0) atomicAdd(&accum[3], v);
        }
        __syncthreads();
    }
}

// ---- combine --------------------------------------------------------------
__global__ void combine(const float* __restrict__ accum, float* __restrict__ out) {
    if (threadIdx.x == 0) {
        const float n = (float)NPTS;
        float sparsity = accum[0] / n;
        float scale    = accum[1] / (3.0f * n);
        float opacl    = accum[2] / n;
        float smooth   = accum[3] / (n * 10.0f);
        out[0] = 0.01f * sparsity + 0.1f * smooth + scale + opacl;
    }
}

extern "C" void kernel_launch(void* const* d_in, const int* in_sizes, int n_in,
                              void* d_out, int out_size, void* d_ws, size_t ws_size,
                              hipStream_t stream)
{
    const float* pos    = (const float*)d_in[0];
    const float* opac   = (const float*)d_in[1];
    const float* scales = (const float*)d_in[2];
    float* out = (float*)d_out;

    char* ws = (char*)d_ws;
    float*    accum  = (float*)ws;
    unsigned* qcnt   = (unsigned*)(ws + 16);
    unsigned* histcnt= (unsigned*)(ws + 256);      // hist -> cnt -> queue
    int*      queue  = (int*)(ws + 256);
    unsigned* base   = (unsigned*)(ws + 131328);
    unsigned* r2m    = (unsigned*)(ws + 262464);
    float4*   sorted = (float4*)(ws + 328064);

    hipMemsetAsync(ws, 0, 131328, stream);

    setup_kernel  <<<NPTS / 256, 256, 0, stream>>>(pos, opac, scales, accum, histcnt);
    prefix_scan   <<<1, 1024, 0, stream>>>(histcnt, base);
    scatter_sorted<<<NPTS / 256, 256, 0, stream>>>(pos, opac, base, histcnt, sorted);
    knn_pass1     <<<NPTS * 8 / 256, 256, 0, stream>>>(sorted, r2m);
    knn_pass2     <<<NPTS / 16, 256, 0, stream>>>(sorted, r2m, base, qcnt, queue, accum);
    knn_heavy     <<<HEAVY_GRID, 256, 0, stream>>>(sorted, r2m, base, qcnt, queue, accum);
    combine       <<<1, 64, 0, stream>>>(accum, out);
}

// Round 4
// 166.215 us; speedup vs baseline: 1.3404x; 1.3404x over previous
//
#include <hip/hip_runtime.h>
#include <stdint.h>

// N=16384 points, K=10 (fixed by setup_inputs).
#define NPTS   16384
#define TOPK   10
#define NBX    32                 // 32x32x32 cells over [-5,5]^3
#define NBK    (32 * 32 * 32)
#define XMIN   (-5.0f)
#define INVBW  (3.2f)             // 32 / 10.0
#define CELLW  (0.3125f)
#define SENT_STEP 0x4000u         // one ulp at masked-key granularity (= idx field)
#define LIGHT_MAX 1024u           // candidate cap for the 16-lane path
#define HEAVY_GRID 128

// ws layout (bytes):
//   0       accum[4] floats (sparsity, scale, opacity, smooth)
//   16      qcnt (uint)            heavy-queue counter
//   20      done (uint)            heavy-block completion counter
//   256     hist[NBK] uint  -> re-zeroed by prefix_scan, reused as cnt,
//                              then DEAD after scatter -> reused as queue[]
//   131328  base[NBK+1] uint
//   262464  r2m[NPTS] uint        (stepped sentinel, written for heavy pts only)
//   328064  sorted[NPTS] float4   (x,y,z,opacity) ordered by (bx,by,bz)
// memset zeroes [0, 131328).

__device__ __forceinline__ unsigned umin_(unsigned a, unsigned b) { return a < b ? a : b; }
__device__ __forceinline__ unsigned umax_(unsigned a, unsigned b) { return a > b ? a : b; }

// Branchless ascending insert (19 independent min/max).
__device__ __forceinline__ void chain_insert(unsigned a[TOPK], unsigned key) {
#pragma unroll
    for (int k = TOPK - 1; k > 0; --k) a[k] = umin_(umax_(a[k - 1], key), a[k]);
    a[0] = umin_(a[0], key);
}

__device__ __forceinline__ void ce_(unsigned &x, unsigned &y) {
    unsigned lo = umin_(x, y); y = umax_(x, y); x = lo;
}

// Bitonic merge network for a length-10 bitonic sequence (15 CEs).
__device__ __forceinline__ void bitonic10(unsigned a[TOPK]) {
    ce_(a[0], a[8]); ce_(a[1], a[9]);
    ce_(a[0], a[4]); ce_(a[1], a[5]); ce_(a[2], a[6]); ce_(a[3], a[7]);
    ce_(a[0], a[2]); ce_(a[1], a[3]); ce_(a[4], a[6]); ce_(a[5], a[7]);
    ce_(a[0], a[1]); ce_(a[2], a[3]); ce_(a[4], a[5]); ce_(a[6], a[7]); ce_(a[8], a[9]);
}

// Merge two sorted 10-lists: ours + partner lane's (halver + bitonic net).
__device__ __forceinline__ void merge_shfl(unsigned a[TOPK], int w) {
    unsigned b[TOPK];
#pragma unroll
    for (int k = 0; k < TOPK; ++k) b[k] = (unsigned)__shfl_xor((int)a[k], w, 64);
#pragma unroll
    for (int k = 0; k < TOPK; ++k) a[k] = umin_(a[k], b[TOPK - 1 - k]);
    bitonic10(a);
}

// Merge a sorted 10-array (same in all lanes) into our sorted top-10.
__device__ __forceinline__ void merge_arr(unsigned a[TOPK], const unsigned* b) {
#pragma unroll
    for (int k = 0; k < TOPK; ++k) a[k] = umin_(a[k], b[TOPK - 1 - k]);
    bitonic10(a);
}

__device__ __forceinline__ int cellf(float v) {
    int b = (int)((v - XMIN) * INVBW);
    return min(max(b, 0), NBX - 1);
}

// ---- fused trivial losses + 3-D cell histogram ----------------------------
__global__ __launch_bounds__(256) void setup_kernel(
    const float* __restrict__ pos, const float* __restrict__ opac,
    const float* __restrict__ scales, float* __restrict__ accum,
    unsigned* __restrict__ hist)
{
    int i = blockIdx.x * 256 + threadIdx.x;
    float o = opac[i];
    float d = o - 0.5f;
    float s_sp = fabsf(o);
    float s_op = d * d;
    float s_sc = fabsf(scales[3 * i] - 1.0f) + fabsf(scales[3 * i + 1] - 1.0f)
               + fabsf(scales[3 * i + 2] - 1.0f);
    int bx = cellf(pos[3 * i]);
    int by = cellf(pos[3 * i + 1]);
    int bz = cellf(pos[3 * i + 2]);
    atomicAdd(&hist[(bx << 10) | (by << 5) | bz], 1u);
#pragma unroll
    for (int off = 32; off > 0; off >>= 1) {
        s_sp += __shfl_down(s_sp, off, 64);
        s_sc += __shfl_down(s_sc, off, 64);
        s_op += __shfl_down(s_op, off, 64);
    }
    if ((threadIdx.x & 63) == 0) {
        atomicAdd(&accum[0], s_sp);
        atomicAdd(&accum[1], s_sc);
        atomicAdd(&accum[2], s_op);
    }
}

// Exclusive scan over 32768 bins: shfl-based (2 barriers total).
// Also re-zeroes hist in place (it becomes the scatter cnt array).
__global__ __launch_bounds__(1024) void prefix_scan(
    unsigned* __restrict__ hist, unsigned* __restrict__ base)
{
    __shared__ unsigned wsum[16];
    const int t = threadIdx.x;
    const int lane = t & 63, wid = t >> 6;
    unsigned loc[32];
    uint4* h4 = (uint4*)(hist + t * 32);
#pragma unroll
    for (int j = 0; j < 8; ++j) {
        uint4 h = h4[j];
        loc[4 * j + 0] = h.x; loc[4 * j + 1] = h.y;
        loc[4 * j + 2] = h.z; loc[4 * j + 3] = h.w;
    }
    unsigned run = 0;
#pragma unroll
    for (int j = 0; j < 32; ++j) { unsigned v = loc[j]; loc[j] = run; run += v; }
    unsigned inc = run;
#pragma unroll
    for (int off = 1; off < 64; off <<= 1) {
        unsigned v = (unsigned)__shfl_up((int)inc, off, 64);
        if (lane >= off) inc += v;
    }
    if (lane == 63) wsum[wid] = inc;
    __syncthreads();
    if (wid == 0) {
        unsigned w = (lane < 16) ? wsum[lane] : 0u;
#pragma unroll
        for (int off = 1; off < 16; off <<= 1) {
            unsigned v = (unsigned)__shfl_up((int)w, off, 64);
            if (lane >= off) w += v;
        }
        if (lane < 16) wsum[lane] = w;
    }
    __syncthreads();
    const unsigned wbase = (wid > 0) ? wsum[wid - 1] : 0u;
    const unsigned tbase = wbase + inc - run;
    uint4* b4 = (uint4*)(base + t * 32);
#pragma unroll
    for (int j = 0; j < 8; ++j) {
        b4[j] = make_uint4(loc[4 * j] + tbase, loc[4 * j + 1] + tbase,
                           loc[4 * j + 2] + tbase, loc[4 * j + 3] + tbase);
        h4[j] = make_uint4(0u, 0u, 0u, 0u);
    }
    if (t == 1023) base[NBK] = NPTS;
}

__global__ __launch_bounds__(256) void scatter_sorted(
    const float* __restrict__ pos, const float* __restrict__ opac,
    const unsigned* __restrict__ base, unsigned* __restrict__ cnt,
    float4* __restrict__ sorted)
{
    int i = blockIdx.x * 256 + threadIdx.x;
    float x = pos[3 * i], y = pos[3 * i + 1], z = pos[3 * i + 2];
    int b = (cellf(x) << 10) | (cellf(y) << 5) | cellf(z);
    unsigned p = base[b] + atomicAdd(&cnt[b], 1u);
    sorted[p] = make_float4(x, y, z, opac[i]);
}

// ---- fused kNN: bound pass + windowed exact scan + smoothness -------------
// 16 lanes/point (4 points/wave).
//  Phase A (bound): top-10 of the +/-128 cell-order window (16 lanes x 16
//    contiguous candidates) -> sentinel (upper bound on true 10-NN key).
//  Phase B (classify): lanes own column-pairs pi = sub+16k (division-free
//    stepping); csum = window candidate count; csum > LIGHT_MAX -> heavy queue.
//  Phase C (scan): each lane scans ITS pairs' z-runs scalar into a private
//    top-10 (pairs parallel across lanes -- no serial pair chain), then the
//    4-level butterfly merge converges the group.
__global__ __launch_bounds__(256) void knn_main(
    const float4* __restrict__ sorted, const unsigned* __restrict__ base,
    unsigned* __restrict__ r2m, unsigned* __restrict__ qcnt,
    int* __restrict__ queue, float* __restrict__ accum)
{
    __shared__ float ssum;
    if (threadIdx.x == 0) ssum = 0.0f;
    __syncthreads();

    const int wv  = threadIdx.x >> 6;
    const int gw  = (threadIdx.x >> 4) & 3;
    const int sub = threadIdx.x & 15;
    const int W   = blockIdx.x * 4 + wv;
    const int Q   = (W * 1531) & 4095;          // balance permutation
    const int s   = Q * 4 + gw;

    const float4 me = sorted[s];

    // ---- phase A: bound ----
    unsigned a[TOPK];
#pragma unroll
    for (int k = 0; k < TOPK; ++k) a[k] = 0xFFFFFFFFu;
    {
        const int dir = sub >> 3;               // 0 right, 1 left
        const int start = 1 + (sub & 7) * 16;
#pragma unroll 4
        for (int t = 0; t < 16; ++t) {
            int p = dir ? (s - start - t) : (s + start + t);
            int pc = min(max(p, 0), NPTS - 1);
            float4 c = sorted[pc];
            float dx = c.x - me.x, dy = c.y - me.y, dz = c.z - me.z;
            float d2 = fmaf(dx, dx, fmaf(dy, dy, dz * dz));
            unsigned key = (__float_as_uint(d2) & 0xFFFFC000u) | (unsigned)pc;
            if (p < 0 || p >= NPTS) key = 0xFFFFFFFFu;
            chain_insert(a, key);
        }
    }
    merge_shfl(a, 1); merge_shfl(a, 2); merge_shfl(a, 4); merge_shfl(a, 8);
    const unsigned sentinel = (a[TOPK - 1] & 0xFFFFC000u) + SENT_STEP;
    const float R = sqrtf(__uint_as_float(sentinel)) + 1e-6f;

    const int bxlo = cellf(me.x - R), bxhi = cellf(me.x + R);
    const int bylo = cellf(me.y - R), byhi = cellf(me.y + R);
    const int bzlo = cellf(me.z - R), bzhi = cellf(me.z + R);
    const int nyw   = byhi - bylo + 1;
    const int npair = (bxhi - bxlo + 1) * nyw;

    // per-lane pair iterator constants (division once, then div-free stepping)
    const int q0  = sub / nyw, r0  = sub - q0 * nyw;
    const int q16 = 16 / nyw,  r16 = 16 - q16 * nyw;

    // ---- phase B: classify ----
    unsigned csum = 0;
    {
        int bx = bxlo + q0, byo = r0;
        for (int pi = sub; pi < npair; pi += 16) {
            int cb = (bx << 10) | ((bylo + byo) << 5);
            csum += base[cb + bzhi + 1] - base[cb + bzlo];
            byo += r16; bx += q16;
            if (byo >= nyw) { byo -= nyw; ++bx; }
        }
    }
#pragma unroll
    for (int off = 1; off <= 8; off <<= 1)
        csum += (unsigned)__shfl_xor((int)csum, off, 64);
    const bool heavy = csum > LIGHT_MAX;
    if (heavy && sub == 0) {
        r2m[s] = sentinel;                       // pass sentinel to heavy path
        unsigned q = atomicAdd(qcnt, 1u);
        queue[q] = s;
    }

    // ---- phase C: per-lane-parallel windowed scan ----
#pragma unroll
    for (int k = 0; k < TOPK; ++k) a[k] = sentinel;
    if (!heavy) {
        int bx = bxlo + q0, byo = r0;
        for (int pi = sub; pi < npair; pi += 16) {
            int cb = (bx << 10) | ((bylo + byo) << 5);
            unsigned lo = base[cb + bzlo], hi = base[cb + bzhi + 1];
            for (unsigned p = lo; p < hi; ++p) {
                float4 c = sorted[p];
                float dx = c.x - me.x, dy = c.y - me.y, dz = c.z - me.z;
                float d2 = fmaf(dx, dx, fmaf(dy, dy, dz * dz));
                unsigned key = (__float_as_uint(d2) & 0xFFFFC000u) | p;
                if (p == (unsigned)s) key = 0xFFFFFFFFu;
                if (key < a[TOPK - 1]) chain_insert(a, key);
            }
            byo += r16; bx += q16;
            if (byo >= nyw) { byo -= nyw; ++bx; }
        }
        merge_shfl(a, 1); merge_shfl(a, 2); merge_shfl(a, 4); merge_shfl(a, 8);
    }

    float v = 0.0f;
    if (!heavy && sub < TOPK) {
        int j = (int)(a[sub] & 0x3FFFu);
        v = fabsf(me.w - sorted[j].w);
    }
    v += __shfl_down(v, 8, 64);
    v += __shfl_down(v, 4, 64);
    v += __shfl_down(v, 2, 64);
    v += __shfl_down(v, 1, 64);
    if (sub == 0) atomicAdd(&ssum, v);
    __syncthreads();
    if (threadIdx.x == 0) atomicAdd(&accum[3], ssum);
}

// ---- heavy path + final combine -------------------------------------------
// One block per queued point. Wave 0 tightens the radius via cell-box
// expansion (smallest m with >= 11 points in [b +/- m]^3 gives
// r10 <= sqrt(3)*(m+1)*w), then 256 lanes scan pairs in parallel; merge
// 64-lane + cross-wave via LDS. Last block to finish computes the output.
__global__ __launch_bounds__(256) void knn_heavy(
    const float4* __restrict__ sorted, const unsigned* __restrict__ r2m,
    const unsigned* __restrict__ base, const unsigned* __restrict__ qcnt,
    const int* __restrict__ queue, float* __restrict__ accum,
    unsigned* __restrict__ done, float* __restrict__ out)
{
    __shared__ unsigned s_top[3][TOPK];
    __shared__ unsigned s_sent;
    const int lane = threadIdx.x & 63;
    const int wid  = threadIdx.x >> 6;
    const int nq   = (int)*qcnt;

    for (int qi = blockIdx.x; qi < nq; qi += HEAVY_GRID) {
        const int s = queue[qi];
        const float4 me = sorted[s];
        const unsigned sent1 = r2m[s];           // already stepped

        if (wid == 0) {
            const int bx = cellf(me.x), by = cellf(me.y), bz = cellf(me.z);
            unsigned sent = sent1;
            for (int m = 1; m < 32; ++m) {
                const int xlo = max(bx - m, 0), xhi = min(bx + m, NBX - 1);
                const int ylo = max(by - m, 0), yhi = min(by + m, NBX - 1);
                const int zlo = max(bz - m, 0), zhi = min(bz + m, NBX - 1);
                const int ny = yhi - ylo + 1;
                const int np = (xhi - xlo + 1) * ny;
                unsigned c = 0;
                for (int pi = lane; pi < np; pi += 64) {
                    int cbx = xlo + pi / ny, cby = ylo + pi % ny;
                    int cb = (cbx << 10) | (cby << 5);
                    c += base[cb + zhi + 1] - base[cb + zlo];
                }
#pragma unroll
                for (int off = 32; off > 0; off >>= 1)
                    c += (unsigned)__shfl_xor((int)c, off, 64);
                if (c >= 11u) {
                    float Rb = CELLW * 1.7320508f * (float)(m + 1);
                    unsigned sb = (__float_as_uint(Rb * Rb) & 0xFFFFC000u) + SENT_STEP;
                    sent = umin_(sent1, sb);
                    break;
                }
            }
            if (lane == 0) s_sent = sent;
        }
        __syncthreads();
        const unsigned sentinel = s_sent;
        const float R = sqrtf(__uint_as_float(sentinel)) + 1e-6f;

        const int bxlo = cellf(me.x - R), bxhi = cellf(me.x + R);
        const int bylo = cellf(me.y - R), byhi = cellf(me.y + R);
        const int bzlo = cellf(me.z - R), bzhi = cellf(me.z + R);
        const int nyw   = byhi - bylo + 1;
        const int npair = (bxhi - bxlo + 1) * nyw;

        unsigned a[TOPK];
#pragma unroll
        for (int k = 0; k < TOPK; ++k) a[k] = sentinel;

        for (int pi = threadIdx.x; pi < npair; pi += 256) {
            int cbx = bxlo + pi / nyw, cby = bylo + pi % nyw;
            int cb = (cbx << 10) | (cby << 5);
            int lo = (int)base[cb + bzlo], hi = (int)base[cb + bzhi + 1];
            for (int p = lo; p < hi; ++p) {
                float4 c = sorted[p];
                float dx = c.x - me.x, dy = c.y - me.y, dz = c.z - me.z;
                float d2 = fmaf(dx, dx, fmaf(dy, dy, dz * dz));
                unsigned key = (__float_as_uint(d2) & 0xFFFFC000u) | (unsigned)p;
                if (p == s) key = 0xFFFFFFFFu;
                if (key < a[TOPK - 1]) chain_insert(a, key);
            }
        }

        merge_shfl(a, 1);  merge_shfl(a, 2);  merge_shfl(a, 4);
        merge_shfl(a, 8);  merge_shfl(a, 16); merge_shfl(a, 32);

        if (wid > 0 && lane == 0) {
#pragma unroll
            for (int k = 0; k < TOPK; ++k) s_top[wid - 1][k] = a[k];
        }
        __syncthreads();
        if (wid == 0) {
            unsigned b[TOPK];
#pragma unroll
            for (int wv = 0; wv < 3; ++wv) {
#pragma unroll
                for (int k = 0; k < TOPK; ++k) b[k] = s_top[wv][k];
                merge_arr(a, b);
            }
            float v = 0.0f;
            if (lane < TOPK) {
                int j = (int)(a[lane] & 0x3FFFu);
                v = fabsf(me.w - sorted[j].w);
            }
            v += __shfl_down(v, 8, 64);
            v += __shfl_down(v, 4, 64);
            v += __shfl_down(v, 2, 64);
            v += __shfl_down(v, 1, 64);
            if (lane == 0) atomicAdd(&accum[3], v);
        }
        __syncthreads();
    }

    // last block to arrive computes the final output (replaces combine kernel)
    __threadfence();
    if (threadIdx.x == 0) {
        unsigned d = atomicAdd(done, 1u);
        if (d == HEAVY_GRID - 1) {
            float sp = atomicAdd(&accum[0], 0.0f);
            float sc = atomicAdd(&accum[1], 0.0f);
            float op = atomicAdd(&accum[2], 0.0f);
            float sm = atomicAdd(&accum[3], 0.0f);
            const float n = (float)NPTS;
            out[0] = 0.01f * (sp / n) + 0.1f * (sm / (n * 10.0f))
                   + sc / (3.0f * n) + op / n;
        }
    }
}

extern "C" void kernel_launch(void* const* d_in, const int* in_sizes, int n_in,
                              void* d_out, int out_size, void* d_ws, size_t ws_size,
                              hipStream_t stream)
{
    const float* pos    = (const float*)d_in[0];
    const float* opac   = (const float*)d_in[1];
    const float* scales = (const float*)d_in[2];
    float* out = (float*)d_out;

    char* ws = (char*)d_ws;
    float*    accum  = (float*)ws;
    unsigned* qcnt   = (unsigned*)(ws + 16);
    unsigned* done   = (unsigned*)(ws + 20);
    unsigned* histcnt= (unsigned*)(ws + 256);      // hist -> cnt -> queue
    int*      queue  = (int*)(ws + 256);
    unsigned* base   = (unsigned*)(ws + 131328);
    unsigned* r2m    = (unsigned*)(ws + 262464);
    float4*   sorted = (float4*)(ws + 328064);

    hipMemsetAsync(ws, 0, 131328, stream);

    setup_kernel  <<<NPTS / 256, 256, 0, stream>>>(pos, opac, scales, accum, histcnt);
    prefix_scan   <<<1, 1024, 0, stream>>>(histcnt, base);
    scatter_sorted<<<NPTS / 256, 256, 0, stream>>>(pos, opac, base, histcnt, sorted);
    knn_main      <<<NPTS * 16 / 256, 256, 0, stream>>>(sorted, base, r2m, qcnt, queue, accum);
    knn_heavy     <<<HEAVY_GRID, 256, 0, stream>>>(sorted, r2m, base, qcnt, queue, accum, done, out);
}